// Round 10
// baseline (301.756 us; speedup 1.0000x reference)
//
#include <hip/hip_runtime.h>
#include <hip/hip_bf16.h>
#include <math.h>

#define B_SZ 2048
#define K_SZ 100000
#define D_SZ 50
#define BT   64       // batch rows per block (8 waves, 512 thr, j=2). r14/r20/r22: finer wave
                      // decomps and per-wave pipelines all regress. Keep the r13/r19 structure.
#define CK   64       // r15 measured CK=128 image: regression. 64-k chunks; r19 pairs two
                      // chunks into one K=32 ph2 (lower/upper MFMA slots, no shuffles).
#define STR  72        // img row stride in 2B units; 144 B
#define MTS  78        // precompute Mt scratch stride (odd dword stride -> ~2-way scatter)
#define SHIFT 30.0f    // bf16 P: fp32 exponent range, no subnormal cliff (f16 failed r4)
#define LOG2E 1.4426950408889634f
#define SHIFT_L2 43.280851226668905f   // SHIFT * LOG2E
#define PSTRIDE 52
#define NCH   1563     // ceil(100000/64)
#define IMG_CH 9216    // 2B units per chunk image: 2 * 64 * STR  ([Mhi bf16 | Mt bf16])
#define IMG_BYTES ((size_t)NCH * IMG_CH * 2)
#define NSEG  18       // 1024B segments per chunk image (18432 B)
#define PART_BYTES ((size_t)B_SZ * PSTRIDE * sizeof(float))

typedef short short8 __attribute__((ext_vector_type(8)));
typedef short short4v __attribute__((ext_vector_type(4)));
typedef float f32x4 __attribute__((ext_vector_type(4)));

__device__ __forceinline__ unsigned short bf16_rne(float f) {
    union { float f; unsigned int u; } v; v.f = f;
    unsigned int r = (v.u + 0x7fffu + ((v.u >> 16) & 1u)) >> 16;
    return (unsigned short)r;
}
__device__ __forceinline__ float bf16_to_f(unsigned short h) {
    union { unsigned int u; float f; } v; v.u = ((unsigned int)h) << 16;
    return v.f;
}

// async global->LDS, 16B per lane; LDS dest = wave-uniform base + lane*16 (m97/m104 semantics)
__device__ __forceinline__ void load_lds16(const void* g, void* l) {
    __builtin_amdgcn_global_load_lds(
        (const __attribute__((address_space(1))) unsigned int*)g,
        (__attribute__((address_space(3))) unsigned int*)l, 16, 0, 0);
}

// ---------------- prologue: M -> per-chunk image [Mhi bf16 | Mt bf16] ----------------
// r7 structure, de-conflicted scatter (MTS=78). NO __threadfence (r11: +120us).
// Zeroes the atomic partial buffer + xtile tickets (folds out the memset dispatch — r21).
__global__ __launch_bounds__(256)
void precompute_m(const float* __restrict__ M, unsigned short* __restrict__ img,
                  float* __restrict__ part, unsigned int* __restrict__ cnt) {
    __shared__ __align__(16) unsigned short Mt[64 * MTS];   // transpose scratch (9984 B)
    const int t = threadIdx.x;
    const int c0 = blockIdx.x;
    const int k0 = c0 * 64;
    for (int i = c0 * 256 + t; i < B_SZ * PSTRIDE; i += NCH * 256) part[i] = 0.f;
    if (c0 == 0 && t < 32) cnt[t] = 0u;
    for (int i = t; i < (64 * MTS) / 2; i += 256) ((unsigned int*)Mt)[i] = 0;
    __syncthreads();
    unsigned int* gh = (unsigned int*)(img + (size_t)c0 * IMG_CH);   // 2304 dwords
    for (int i = t; i < 64 * 36; i += 256) {
        int r = i / 36, cd = i - r * 36, c = cd * 2;
        int kg = k0 + r;
        unsigned int val = 0;
        if (kg < K_SZ && c < D_SZ) {
            float2 v = *(const float2*)&M[(size_t)kg * D_SZ + c];
            val = ((unsigned int)bf16_rne(v.y) << 16) | bf16_rne(v.x);
            Mt[c * MTS + r]       = (unsigned short)(val & 0xffffu);  // one-time transpose
            Mt[(c + 1) * MTS + r] = (unsigned short)(val >> 16);
        }
        gh[i] = val;
    }
    __syncthreads();
    // copy-out: image d-row r, dwords c=0..35 (u16 pairs 2c,2c+1; cols >=64 are zero pad)
    unsigned int* gt = (unsigned int*)(img + (size_t)c0 * IMG_CH + 64 * STR);
    for (int i = t; i < 64 * 36; i += 256) {
        int r = i / 36, c = i - r * 36;
        gt[i] = *(const unsigned int*)&Mt[r * MTS + c * 2];   // dword-aligned (MTS even)
    }
}

// ---------------- hot kernel (r19 body verbatim + r23 last-block combine) ----------------
// ph1: S[mem][batch] = Mhi . (xh + xl)^T per chunk (2-pass x-side hi/lo). exp in regs.
// ph2: ONE K=32 16x16x32 MFMA pass per chunk PAIR (lower/upper 4 A/B slots = chunks n/n+1;
//      slot pairing is k-agnostic). Staging: r18 quad-buffer, drain+barrier per pair.
// r23: combine folded into the epilogue — total-minus-attend has been a constant ~63us
// across 12 rounds (~10-13us PER-DISPATCH overhead x4 + combine); last contributor block
// per xtile (threadfence + atomic ticket, rocPRIM pattern) normalizes and writes out.
// Cross-XCD safety: final values re-read via atomicAdd(p, 0.f) — same proven-coherent
// primitive as the accumulation; plain loads could hit a stale L2 line.
// launch_bounds MUST stay (512,4): r16 measured (512,8) -> 32-VGPR alloc, x-frag spill,
// 1.9GB scratch FETCH, 577us.
__global__ __launch_bounds__(512, 4)
void attend_fast(const float* __restrict__ x, const unsigned short* __restrict__ img,
                 float* __restrict__ part, unsigned int* __restrict__ cnt,
                 float* __restrict__ out, int slice, int nsplit) {
    __shared__ __align__(16) unsigned short lds[4 * IMG_CH];   // quad-buf; buf0/1 reused as Ured
    __shared__ float lsc[4][64];
    __shared__ float Lrow[64];
    __shared__ int lastFlag;

    const int t = threadIdx.x;
    const int w = t >> 6, lane = t & 63;
    const int quad = lane >> 4, lq = lane & 15;

    const int bid = blockIdx.x;
    const int rr = bid >> 3;
    const int split = (rr >> 5) * 8 + (bid & 7);   // same split -> same XCD (perf heuristic)
    const int xtile = rr & 31;
    const int b0 = xtile * BT;
    const int kbeg = split * slice;
    const int kend = min(kbeg + slice, K_SZ);

    const int nt0 = (w & 1) * 2;   // this wave's pair of batch 16-tiles
    const int mblk = w >> 1;       // this wave's memrow 16-tile (= its ph2 k-slice)

    // x fragments: direct global load + hi/lo bf16 split (K-loop invariant, cold path)
    short8 xh[2][2], xl[2][2];
    for (int j = 0; j < 2; ++j) {
        int row = b0 + (nt0 + j) * 16 + lq;
        const float* xr = x + (size_t)row * D_SZ;
        for (int ki = 0; ki < 2; ++ki) {
            int d0 = ki * 32 + quad * 8;
            float v[8];
#pragma unroll
            for (int e = 0; e < 8; ++e) v[e] = 0.f;
            if (d0 + 8 <= D_SZ) {
#pragma unroll
                for (int e = 0; e < 4; ++e) {
                    float2 f2 = *(const float2*)&xr[d0 + 2 * e];
                    v[2 * e] = f2.x; v[2 * e + 1] = f2.y;
                }
            } else if (d0 < D_SZ) {            // d0 == 48
                float2 f2 = *(const float2*)&xr[d0];
                v[0] = f2.x; v[1] = f2.y;
            }
            short8 sh, sl;
#pragma unroll
            for (int e = 0; e < 8; ++e) {
                unsigned short h = bf16_rne(v[e]);
                sh[e] = (short)h;
                sl[e] = (short)bf16_rne(v[e] - bf16_to_f(h));
            }
            xh[j][ki] = sh; xl[j][ki] = sl;
        }
    }

    f32x4 Uacc[2][4] = {};         // [batch tile j][d tile dt], partial over k-slice mblk
    float lac[2] = {0.f, 0.f};

    const int ci0 = kbeg >> 6;
    const int nch = (kend - kbeg + CK - 1) / CK;
    const int r0 = bid % nch;      // per-block rotation (de-phase co-resident blocks)

    // prologue DMA: rotated chunks seq[0] -> buf0, seq[1] -> buf1
    {
        const unsigned short* g = img + (size_t)(ci0 + r0) * IMG_CH;
        for (int seg = w; seg < NSEG; seg += 8)
            load_lds16((const unsigned int*)(g + seg * 512) + lane * 4, lds + seg * 512);
        if (nch > 1) {
            int c1 = r0 + 1; if (c1 >= nch) c1 -= nch;
            const unsigned short* g1 = img + (size_t)(ci0 + c1) * IMG_CH;
            for (int seg = w; seg < NSEG; seg += 8)
                load_lds16((const unsigned int*)(g1 + seg * 512) + lane * 4,
                           lds + IMG_CH + seg * 512);
        }
    }

    const int aoff0 = (mblk * 16 + lq) * STR + quad * 8;           // ph1 Mhi read base
    const int boffb = mblk * 16 + quad * 4;                        // ph2 Mt k-col base

    for (int n = 0; n < nch; n += 2) {
        __builtin_amdgcn_s_waitcnt(0);   // drain own DMA (vm+lgkm) — issued >=1 pair ago
        __syncthreads();                 // chunks n,n+1 visible; fences last pair's reads
                                         // of the two buffers we are about to overwrite
#pragma unroll
        for (int f = 2; f <= 3; ++f) {   // prefetch chunks n+2, n+3 (rotated order)
            int nn = n + f;
            if (nn < nch) {
                int cc = r0 + nn; if (cc >= nch) cc -= nch;
                const unsigned short* g = img + (size_t)(ci0 + cc) * IMG_CH;
                unsigned short* dst = lds + (size_t)(nn & 3) * IMG_CH;
                for (int seg = w; seg < NSEG; seg += 8)
                    load_lds16((const unsigned int*)(g + seg * 512) + lane * 4,
                               dst + seg * 512);
            }
        }

        const int hasB = (n + 1 < nch);                 // block-uniform
        const unsigned short* MhiA = lds + (size_t)(n & 3) * IMG_CH;
        const unsigned short* MtA  = MhiA + 64 * STR;
        const unsigned short* MhiB = lds + (size_t)((n + 1) & 3) * IMG_CH;
        const unsigned short* MtB  = MhiB + 64 * STR;

        // ---- chunk A: ph1 + exp -> paA (packed bf16 pairs, regs 0..1 of the pair op)
        unsigned int paA[2][2];
        {
            f32x4 S[2] = {};
#pragma unroll
            for (int ki = 0; ki < 2; ++ki) {
                short8 ah = *(const short8*)&MhiA[aoff0 + ki * 32];
#pragma unroll
                for (int j = 0; j < 2; ++j) {
                    S[j] = __builtin_amdgcn_mfma_f32_16x16x32_bf16(ah, xh[j][ki], S[j], 0, 0, 0);
                    S[j] = __builtin_amdgcn_mfma_f32_16x16x32_bf16(ah, xl[j][ki], S[j], 0, 0, 0);
                }
            }
#pragma unroll
            for (int j = 0; j < 2; ++j) {
                float p0 = __builtin_amdgcn_exp2f(fmaf(S[j][0], LOG2E, -SHIFT_L2));
                float p1 = __builtin_amdgcn_exp2f(fmaf(S[j][1], LOG2E, -SHIFT_L2));
                float p2 = __builtin_amdgcn_exp2f(fmaf(S[j][2], LOG2E, -SHIFT_L2));
                float p3 = __builtin_amdgcn_exp2f(fmaf(S[j][3], LOG2E, -SHIFT_L2));
                lac[j] += (p0 + p1) + (p2 + p3);
                __hip_bfloat162 q01 = __float22bfloat162_rn(make_float2(p0, p1));
                __hip_bfloat162 q23 = __float22bfloat162_rn(make_float2(p2, p3));
                __builtin_memcpy(&paA[j][0], &q01, 4);
                __builtin_memcpy(&paA[j][1], &q23, 4);
            }
        }

        // ---- chunk B: ph1 + exp -> paB (regs 2..3); zeros on the odd tail
        unsigned int paB[2][2] = {{0u, 0u}, {0u, 0u}};
        if (hasB) {
            f32x4 S[2] = {};
#pragma unroll
            for (int ki = 0; ki < 2; ++ki) {
                short8 ah = *(const short8*)&MhiB[aoff0 + ki * 32];
#pragma unroll
                for (int j = 0; j < 2; ++j) {
                    S[j] = __builtin_amdgcn_mfma_f32_16x16x32_bf16(ah, xh[j][ki], S[j], 0, 0, 0);
                    S[j] = __builtin_amdgcn_mfma_f32_16x16x32_bf16(ah, xl[j][ki], S[j], 0, 0, 0);
                }
            }
#pragma unroll
            for (int j = 0; j < 2; ++j) {
                float p0 = __builtin_amdgcn_exp2f(fmaf(S[j][0], LOG2E, -SHIFT_L2));
                float p1 = __builtin_amdgcn_exp2f(fmaf(S[j][1], LOG2E, -SHIFT_L2));
                float p2 = __builtin_amdgcn_exp2f(fmaf(S[j][2], LOG2E, -SHIFT_L2));
                float p3 = __builtin_amdgcn_exp2f(fmaf(S[j][3], LOG2E, -SHIFT_L2));
                lac[j] += (p0 + p1) + (p2 + p3);
                __hip_bfloat162 q01 = __float22bfloat162_rn(make_float2(p0, p1));
                __hip_bfloat162 q23 = __float22bfloat162_rn(make_float2(p2, p3));
                __builtin_memcpy(&paB[j][0], &q01, 4);
                __builtin_memcpy(&paB[j][1], &q23, 4);
            }
        }

        // ---- combined ph2: U += [P_A | P_B] . [Mt_A | Mt_B], 8 full-rate K=32 MFMAs
#pragma unroll
        for (int dt = 0; dt < 4; ++dt) {
            int boff = (dt * 16 + lq) * STR + boffb;   // 8B-aligned
            union { short8 s8; unsigned int u[4]; } bm;
            bm.u[0] = *(const unsigned int*)&MtA[boff];
            bm.u[1] = *(const unsigned int*)&MtA[boff + 2];
            bm.u[2] = *(const unsigned int*)&MtB[boff];       // stale on tail: x0 below
            bm.u[3] = *(const unsigned int*)&MtB[boff + 2];
#pragma unroll
            for (int j = 0; j < 2; ++j) {
                union { short8 s8; unsigned int u[4]; } pa;
                pa.u[0] = paA[j][0]; pa.u[1] = paA[j][1];
                pa.u[2] = paB[j][0]; pa.u[3] = paB[j][1];
                Uacc[j][dt] = __builtin_amdgcn_mfma_f32_16x16x32_bf16(pa.s8, bm.s8, Uacc[j][dt], 0, 0, 0);
            }
        }
    }

    // l reduction across quads (lane^16, lane^32 share a batch column)
    for (int j = 0; j < 2; ++j) {
        float v = lac[j];
        v += __shfl_xor(v, 16);
        v += __shfl_xor(v, 32);
        if (quad == 0) lsc[mblk][(nt0 + j) * 16 + lq] = v;
    }

    // U reduction across the 4 k-slice waves, in LDS (reuse buf0/1 as float [64][66])
    float* Ured = (float*)lds;
#pragma unroll
    for (int rnd = 0; rnd < 4; ++rnd) {
        __syncthreads();
        if (mblk == rnd) {
#pragma unroll
            for (int j = 0; j < 2; ++j)
#pragma unroll
                for (int dt = 0; dt < 4; ++dt)
#pragma unroll
                    for (int r4 = 0; r4 < 4; ++r4) {
                        int row = (nt0 + j) * 16 + quad * 4 + r4;
                        int col = dt * 16 + lq;
                        if (rnd == 0) Ured[row * 66 + col] = Uacc[j][dt][r4];
                        else          Ured[row * 66 + col] += Uacc[j][dt][r4];
                    }
        }
    }
    __syncthreads();

    // atomic-accumulate partials into the single [2048][52] buffer (r17; ulp-level order)
    float* pp = part + (size_t)b0 * PSTRIDE;
    for (int i = t; i < BT * D_SZ; i += 512) {
        int row = i / D_SZ, d = i - row * D_SZ;
        atomicAdd(&pp[(size_t)row * PSTRIDE + d], Ured[row * 66 + d]);
    }
    if (t < BT) {
        float Ls = lsc[0][t] + lsc[1][t] + lsc[2][t] + lsc[3][t];
        atomicAdd(&pp[(size_t)t * PSTRIDE + D_SZ], Ls);
    }

    // r23: last contributor block per xtile normalizes + writes out (threadfence+ticket,
    // rocPRIM pattern; final reads via atomicAdd(p,0.f) for cross-XCD coherence)
    __threadfence();
    __syncthreads();
    if (t == 0) {
        unsigned int old = atomicAdd(&cnt[xtile], 1u);
        lastFlag = (old == (unsigned int)(nsplit - 1));
    }
    __syncthreads();
    if (lastFlag) {
        __threadfence();
        if (t < BT) Lrow[t] = atomicAdd(&pp[(size_t)t * PSTRIDE + D_SZ], 0.f);
        __syncthreads();
        for (int i = t; i < BT * D_SZ; i += 512) {
            int row = i / D_SZ, d = i - row * D_SZ;
            int gb = b0 + row;
            float acc = atomicAdd(&pp[(size_t)row * PSTRIDE + d], 0.f);
            out[(size_t)gb * (2 * D_SZ) + d] = x[(size_t)gb * D_SZ + d];
            out[(size_t)gb * (2 * D_SZ) + D_SZ + d] = acc / Lrow[row];
        }
    }
}

// ---------------- fallback (round-2 kernel) for small ws ----------------
__global__ __launch_bounds__(512, 4)
void attend_partial_v2(const float* __restrict__ x, const float* __restrict__ M,
                       float* __restrict__ part, int slice) {
    __shared__ __align__(16) unsigned short lds[4 * 64 * STR];
    __shared__ float lsc[4][64];
    unsigned short* bufA  = lds;
    unsigned short* bufB  = lds + 64 * STR;
    unsigned short* Mc_hi = lds + 2 * 64 * STR;
    unsigned short* Mc_lo = lds + 3 * 64 * STR;

    const int t = threadIdx.x;
    const int w = t >> 6, lane = t & 63;
    const int quad = lane >> 4, lq = lane & 15;
    const int b0 = blockIdx.x * 64;
    const int split = blockIdx.y;
    const int kbeg = split * slice;
    const int kend = min(kbeg + slice, K_SZ);

    for (int i = t; i < 4 * 64 * STR; i += 512) lds[i] = 0;
    __syncthreads();
    for (int i = t; i < 64 * 25; i += 512) {
        int r = i / 25, cp = i - r * 25, c = cp * 2;
        float2 v = *(const float2*)&x[(size_t)(b0 + r) * D_SZ + c];
        unsigned short h0 = bf16_rne(v.x), h1 = bf16_rne(v.y);
        unsigned short l0 = bf16_rne(v.x - bf16_to_f(h0));
        unsigned short l1 = bf16_rne(v.y - bf16_to_f(h1));
        *(unsigned int*)&bufA[r * STR + c] = ((unsigned int)h1 << 16) | h0;
        *(unsigned int*)&bufB[r * STR + c] = ((unsigned int)l1 << 16) | l0;
    }
    __syncthreads();

    const int nt0 = (w & 1) * 2;
    const int mblk = w >> 1;
    short8 xh[2][2], xl[2][2];
    for (int j = 0; j < 2; ++j)
        for (int ki = 0; ki < 2; ++ki) {
            int off = ((nt0 + j) * 16 + lq) * STR + ki * 32 + quad * 8;
            xh[j][ki] = *(const short8*)&bufA[off];
            xl[j][ki] = *(const short8*)&bufB[off];
        }

    f32x4 Uacc[2] = {};
    float lac[2] = {0.f, 0.f};

    for (int k0 = kbeg; k0 < kend; k0 += CK) {
        __syncthreads();
        for (int i = t; i < 64 * 25; i += 512) {
            int r = i / 25, cp = i - r * 25, c = cp * 2;
            int kg = k0 + r;
            float2 v = make_float2(0.f, 0.f);
            if (kg < kend) v = *(const float2*)&M[(size_t)kg * D_SZ + c];
            unsigned short h0 = bf16_rne(v.x), h1 = bf16_rne(v.y);
            unsigned short l0 = bf16_rne(v.x - bf16_to_f(h0));
            unsigned short l1 = bf16_rne(v.y - bf16_to_f(h1));
            *(unsigned int*)&Mc_hi[r * STR + c] = ((unsigned int)h1 << 16) | h0;
            *(unsigned int*)&Mc_lo[r * STR + c] = ((unsigned int)l1 << 16) | l0;
            bufB[c * STR + r] = h0;
            bufB[(c + 1) * STR + r] = h1;
        }
        __syncthreads();

        f32x4 S[2] = {};
        for (int ki = 0; ki < 2; ++ki) {
            int aoff = (mblk * 16 + lq) * STR + ki * 32 + quad * 8;
            short8 ah = *(const short8*)&Mc_hi[aoff];
            short8 al = *(const short8*)&Mc_lo[aoff];
            for (int j = 0; j < 2; ++j) {
                S[j] = __builtin_amdgcn_mfma_f32_16x16x32_bf16(ah, xh[j][ki], S[j], 0, 0, 0);
                S[j] = __builtin_amdgcn_mfma_f32_16x16x32_bf16(ah, xl[j][ki], S[j], 0, 0, 0);
                S[j] = __builtin_amdgcn_mfma_f32_16x16x32_bf16(al, xh[j][ki], S[j], 0, 0, 0);
            }
        }
        for (int j = 0; j < 2; ++j) {
            unsigned short pb4[4];
#pragma unroll
            for (int r4 = 0; r4 < 4; ++r4) {
                float p = __expf(S[j][r4] - SHIFT);
                lac[j] += p;
                pb4[r4] = bf16_rne(p);
            }
            int b = (nt0 + j) * 16 + lq;
            int n0 = mblk * 16 + quad * 4;
            *(unsigned int*)&bufA[b * STR + n0]     = ((unsigned int)pb4[1] << 16) | pb4[0];
            *(unsigned int*)&bufA[b * STR + n0 + 2] = ((unsigned int)pb4[3] << 16) | pb4[2];
        }
        __syncthreads();
        for (int ki = 0; ki < 2; ++ki) {
            int poff = (mblk * 16 + lq) * STR + ki * 32 + quad * 8;
            short8 ap = *(const short8*)&bufA[poff];
            for (int j = 0; j < 2; ++j) {
                int doff = ((nt0 + j) * 16 + lq) * STR + ki * 32 + quad * 8;
                short8 bm = *(const short8*)&bufB[doff];
                Uacc[j] = __builtin_amdgcn_mfma_f32_16x16x32_bf16(ap, bm, Uacc[j], 0, 0, 0);
            }
        }
    }

    for (int j = 0; j < 2; ++j) {
        float v = lac[j];
        v += __shfl_xor(v, 16);
        v += __shfl_xor(v, 32);
        if (quad == 0) lsc[mblk][(nt0 + j) * 16 + lq] = v;
    }
    __syncthreads();
    float* pp = part + ((size_t)split * B_SZ + b0) * PSTRIDE;
    for (int j = 0; j < 2; ++j) {
        int d = (nt0 + j) * 16 + lq;
        if (d < D_SZ) {
#pragma unroll
            for (int r4 = 0; r4 < 4; ++r4) {
                int b = mblk * 16 + quad * 4 + r4;
                pp[(size_t)b * PSTRIDE + d] = Uacc[j][r4];
            }
        }
    }
    if (t < 64) {
        float Ls = lsc[0][t] + lsc[1][t] + lsc[2][t] + lsc[3][t];
        pp[(size_t)t * PSTRIDE + D_SZ] = Ls;
    }
}

// combine for the fallback path: per-split partial slots
__global__ __launch_bounds__(256)
void combine(const float* __restrict__ x, const float* __restrict__ part,
             float* __restrict__ out, int nsplit) {
    const int b = blockIdx.x * 4 + (threadIdx.x >> 6);
    const int t = threadIdx.x & 63;
    float L = 0.f;
    for (int s = 0; s < nsplit; ++s)
        L += part[((size_t)s * B_SZ + b) * PSTRIDE + D_SZ];
    if (t < D_SZ) {
        float acc = 0.f;
        for (int s = 0; s < nsplit; ++s)
            acc += part[((size_t)s * B_SZ + b) * PSTRIDE + t];
        out[(size_t)b * (2 * D_SZ) + t] = x[(size_t)b * D_SZ + t];
        out[(size_t)b * (2 * D_SZ) + D_SZ + t] = acc / L;
    }
}

extern "C" void kernel_launch(void* const* d_in, const int* in_sizes, int n_in,
                              void* d_out, int out_size, void* d_ws, size_t ws_size,
                              hipStream_t stream) {
    const float* x = (const float*)d_in[0];
    const float* M = (const float*)d_in[1];
    float* out = (float*)d_out;
    const size_t per_split = (size_t)B_SZ * PSTRIDE * sizeof(float);

    if (ws_size >= IMG_BYTES + PART_BYTES + 128) {
        unsigned short* img = (unsigned short*)d_ws;
        float* part = (float*)((char*)d_ws + IMG_BYTES);
        unsigned int* cnt = (unsigned int*)((char*)d_ws + IMG_BYTES + PART_BYTES);
        const int ns = 32;
        int slice = (((K_SZ + ns - 1) / ns) + 127) & ~127;   // 3200: 128-aligned
        precompute_m<<<NCH, 256, 0, stream>>>(M, img, part, cnt);  // also zeroes part+cnt
        attend_fast<<<32 * ns, 512, 0, stream>>>(x, img, part, cnt, out, slice, ns);
    } else {
        float* part = (float*)d_ws;
        int ns = (int)(ws_size / per_split);
        if (ns > 32) ns = 32;
        if (ns < 1) ns = 1;
        int slice = (K_SZ + ns - 1) / ns;
        dim3 gridA(B_SZ / 64, ns);
        attend_partial_v2<<<gridA, 512, 0, stream>>>(x, M, part, slice);
        combine<<<B_SZ / 4, 256, 0, stream>>>(x, part, out, ns);
    }
}

// Round 11
// 178.875 us; speedup vs baseline: 1.6870x; 1.6870x over previous
//
#include <hip/hip_runtime.h>
#include <hip/hip_bf16.h>
#include <math.h>

#define B_SZ 2048
#define K_SZ 100000
#define D_SZ 50
#define BT   64       // batch rows per block (8 waves, 512 thr, j=2). r14/r20/r22: finer wave
                      // decomps and per-wave pipelines all regress. Keep the r13/r19 structure.
#define CK   64       // r15 measured CK=128 image: regression. 64-k chunks; r19 pairs two
                      // chunks into one K=32 ph2 (lower/upper MFMA slots, no shuffles).
#define STR  72        // img row stride in 2B units; 144 B
#define MTS  78        // precompute Mt scratch stride (odd dword stride -> ~2-way scatter)
#define SHIFT 30.0f    // bf16 P: fp32 exponent range, no subnormal cliff (f16 failed r4)
#define LOG2E 1.4426950408889634f
#define SHIFT_L2 43.280851226668905f   // SHIFT * LOG2E
#define PSTRIDE 52
#define NCH   1563     // ceil(100000/64)
#define IMG_CH 9216    // 2B units per chunk image: 2 * 64 * STR  ([Mhi bf16 | Mt bf16])
#define IMG_BYTES ((size_t)NCH * IMG_CH * 2)
#define NSEG  18       // 1024B segments per chunk image (18432 B)
#define PART_BYTES ((size_t)B_SZ * PSTRIDE * sizeof(float))

typedef short short8 __attribute__((ext_vector_type(8)));
typedef short short4v __attribute__((ext_vector_type(4)));
typedef float f32x4 __attribute__((ext_vector_type(4)));

__device__ __forceinline__ unsigned short bf16_rne(float f) {
    union { float f; unsigned int u; } v; v.f = f;
    unsigned int r = (v.u + 0x7fffu + ((v.u >> 16) & 1u)) >> 16;
    return (unsigned short)r;
}
__device__ __forceinline__ float bf16_to_f(unsigned short h) {
    union { unsigned int u; float f; } v; v.u = ((unsigned int)h) << 16;
    return v.f;
}

// async global->LDS, 16B per lane; LDS dest = wave-uniform base + lane*16 (m97/m104 semantics)
__device__ __forceinline__ void load_lds16(const void* g, void* l) {
    __builtin_amdgcn_global_load_lds(
        (const __attribute__((address_space(1))) unsigned int*)g,
        (__attribute__((address_space(3))) unsigned int*)l, 16, 0, 0);
}

// ---------------- prologue: M -> per-chunk image [Mhi bf16 | Mt bf16] ----------------
// r7 structure, de-conflicted scatter (MTS=78). NO __threadfence (r11: +120us — and r23
// re-measured the same failure in attend's epilogue: per-block L2 writeback serialized,
// 113->255us. NEVER use __threadfence in a per-block path on this chip.)
// Zeroes the atomic partial buffer + xtile tickets (folds out the memset dispatch — r21).
__global__ __launch_bounds__(256)
void precompute_m(const float* __restrict__ M, unsigned short* __restrict__ img,
                  float* __restrict__ part, unsigned int* __restrict__ cnt) {
    __shared__ __align__(16) unsigned short Mt[64 * MTS];   // transpose scratch (9984 B)
    const int t = threadIdx.x;
    const int c0 = blockIdx.x;
    const int k0 = c0 * 64;
    for (int i = c0 * 256 + t; i < B_SZ * PSTRIDE; i += NCH * 256) part[i] = 0.f;
    if (c0 == 0 && t < 32) cnt[t] = 0u;
    for (int i = t; i < (64 * MTS) / 2; i += 256) ((unsigned int*)Mt)[i] = 0;
    __syncthreads();
    unsigned int* gh = (unsigned int*)(img + (size_t)c0 * IMG_CH);   // 2304 dwords
    for (int i = t; i < 64 * 36; i += 256) {
        int r = i / 36, cd = i - r * 36, c = cd * 2;
        int kg = k0 + r;
        unsigned int val = 0;
        if (kg < K_SZ && c < D_SZ) {
            float2 v = *(const float2*)&M[(size_t)kg * D_SZ + c];
            val = ((unsigned int)bf16_rne(v.y) << 16) | bf16_rne(v.x);
            Mt[c * MTS + r]       = (unsigned short)(val & 0xffffu);  // one-time transpose
            Mt[(c + 1) * MTS + r] = (unsigned short)(val >> 16);
        }
        gh[i] = val;
    }
    __syncthreads();
    // copy-out: image d-row r, dwords c=0..35 (u16 pairs 2c,2c+1; cols >=64 are zero pad)
    unsigned int* gt = (unsigned int*)(img + (size_t)c0 * IMG_CH + 64 * STR);
    for (int i = t; i < 64 * 36; i += 256) {
        int r = i / 36, c = i - r * 36;
        gt[i] = *(const unsigned int*)&Mt[r * MTS + c * 2];   // dword-aligned (MTS even)
    }
}

// ---------------- hot kernel (r19 body verbatim + r24 last-block combine) ----------------
// ph1: S[mem][batch] = Mhi . (xh + xl)^T per chunk (2-pass x-side hi/lo). exp in regs.
// ph2: ONE K=32 16x16x32 MFMA pass per chunk PAIR (lower/upper 4 A/B slots = chunks n/n+1;
//      slot pairing is k-agnostic). Staging: r18 quad-buffer, drain+barrier per pair.
// r24: combine folded into the epilogue via ticket, but ordering by per-wave
// s_waitcnt vmcnt(0) — NOT __threadfence (r23: threadfence's per-block L2 writeback
// serialized 1024 blocks, attend 113->255us). Device-scope atomics are vmem ops: once a
// wave's vmcnt drains they are COMPLETE at the coherence point; the ticket atomic issued
// after is therefore ordered. Last block's final reads use atomicAdd(p,0.f) (coherent
// reads through the same point — plain loads could hit a stale per-XCD L2 line).
// launch_bounds MUST stay (512,4): r16 measured (512,8) -> 32-VGPR alloc, x-frag spill,
// 1.9GB scratch FETCH, 577us.
__global__ __launch_bounds__(512, 4)
void attend_fast(const float* __restrict__ x, const unsigned short* __restrict__ img,
                 float* __restrict__ part, unsigned int* __restrict__ cnt,
                 float* __restrict__ out, int slice, int nsplit) {
    __shared__ __align__(16) unsigned short lds[4 * IMG_CH];   // quad-buf; buf0/1 reused as Ured
    __shared__ float lsc[4][64];
    __shared__ float Lrow[64];
    __shared__ int lastFlag;

    const int t = threadIdx.x;
    const int w = t >> 6, lane = t & 63;
    const int quad = lane >> 4, lq = lane & 15;

    const int bid = blockIdx.x;
    const int rr = bid >> 3;
    const int split = (rr >> 5) * 8 + (bid & 7);   // same split -> same XCD (perf heuristic)
    const int xtile = rr & 31;
    const int b0 = xtile * BT;
    const int kbeg = split * slice;
    const int kend = min(kbeg + slice, K_SZ);

    const int nt0 = (w & 1) * 2;   // this wave's pair of batch 16-tiles
    const int mblk = w >> 1;       // this wave's memrow 16-tile (= its ph2 k-slice)

    // x fragments: direct global load + hi/lo bf16 split (K-loop invariant, cold path)
    short8 xh[2][2], xl[2][2];
    for (int j = 0; j < 2; ++j) {
        int row = b0 + (nt0 + j) * 16 + lq;
        const float* xr = x + (size_t)row * D_SZ;
        for (int ki = 0; ki < 2; ++ki) {
            int d0 = ki * 32 + quad * 8;
            float v[8];
#pragma unroll
            for (int e = 0; e < 8; ++e) v[e] = 0.f;
            if (d0 + 8 <= D_SZ) {
#pragma unroll
                for (int e = 0; e < 4; ++e) {
                    float2 f2 = *(const float2*)&xr[d0 + 2 * e];
                    v[2 * e] = f2.x; v[2 * e + 1] = f2.y;
                }
            } else if (d0 < D_SZ) {            // d0 == 48
                float2 f2 = *(const float2*)&xr[d0];
                v[0] = f2.x; v[1] = f2.y;
            }
            short8 sh, sl;
#pragma unroll
            for (int e = 0; e < 8; ++e) {
                unsigned short h = bf16_rne(v[e]);
                sh[e] = (short)h;
                sl[e] = (short)bf16_rne(v[e] - bf16_to_f(h));
            }
            xh[j][ki] = sh; xl[j][ki] = sl;
        }
    }

    f32x4 Uacc[2][4] = {};         // [batch tile j][d tile dt], partial over k-slice mblk
    float lac[2] = {0.f, 0.f};

    const int ci0 = kbeg >> 6;
    const int nch = (kend - kbeg + CK - 1) / CK;
    const int r0 = bid % nch;      // per-block rotation (de-phase co-resident blocks)

    // prologue DMA: rotated chunks seq[0] -> buf0, seq[1] -> buf1
    {
        const unsigned short* g = img + (size_t)(ci0 + r0) * IMG_CH;
        for (int seg = w; seg < NSEG; seg += 8)
            load_lds16((const unsigned int*)(g + seg * 512) + lane * 4, lds + seg * 512);
        if (nch > 1) {
            int c1 = r0 + 1; if (c1 >= nch) c1 -= nch;
            const unsigned short* g1 = img + (size_t)(ci0 + c1) * IMG_CH;
            for (int seg = w; seg < NSEG; seg += 8)
                load_lds16((const unsigned int*)(g1 + seg * 512) + lane * 4,
                           lds + IMG_CH + seg * 512);
        }
    }

    const int aoff0 = (mblk * 16 + lq) * STR + quad * 8;           // ph1 Mhi read base
    const int boffb = mblk * 16 + quad * 4;                        // ph2 Mt k-col base

    for (int n = 0; n < nch; n += 2) {
        __builtin_amdgcn_s_waitcnt(0);   // drain own DMA (vm+lgkm) — issued >=1 pair ago
        __syncthreads();                 // chunks n,n+1 visible; fences last pair's reads
                                         // of the two buffers we are about to overwrite
#pragma unroll
        for (int f = 2; f <= 3; ++f) {   // prefetch chunks n+2, n+3 (rotated order)
            int nn = n + f;
            if (nn < nch) {
                int cc = r0 + nn; if (cc >= nch) cc -= nch;
                const unsigned short* g = img + (size_t)(ci0 + cc) * IMG_CH;
                unsigned short* dst = lds + (size_t)(nn & 3) * IMG_CH;
                for (int seg = w; seg < NSEG; seg += 8)
                    load_lds16((const unsigned int*)(g + seg * 512) + lane * 4,
                               dst + seg * 512);
            }
        }

        const int hasB = (n + 1 < nch);                 // block-uniform
        const unsigned short* MhiA = lds + (size_t)(n & 3) * IMG_CH;
        const unsigned short* MtA  = MhiA + 64 * STR;
        const unsigned short* MhiB = lds + (size_t)((n + 1) & 3) * IMG_CH;
        const unsigned short* MtB  = MhiB + 64 * STR;

        // ---- chunk A: ph1 + exp -> paA (packed bf16 pairs, regs 0..1 of the pair op)
        unsigned int paA[2][2];
        {
            f32x4 S[2] = {};
#pragma unroll
            for (int ki = 0; ki < 2; ++ki) {
                short8 ah = *(const short8*)&MhiA[aoff0 + ki * 32];
#pragma unroll
                for (int j = 0; j < 2; ++j) {
                    S[j] = __builtin_amdgcn_mfma_f32_16x16x32_bf16(ah, xh[j][ki], S[j], 0, 0, 0);
                    S[j] = __builtin_amdgcn_mfma_f32_16x16x32_bf16(ah, xl[j][ki], S[j], 0, 0, 0);
                }
            }
#pragma unroll
            for (int j = 0; j < 2; ++j) {
                float p0 = __builtin_amdgcn_exp2f(fmaf(S[j][0], LOG2E, -SHIFT_L2));
                float p1 = __builtin_amdgcn_exp2f(fmaf(S[j][1], LOG2E, -SHIFT_L2));
                float p2 = __builtin_amdgcn_exp2f(fmaf(S[j][2], LOG2E, -SHIFT_L2));
                float p3 = __builtin_amdgcn_exp2f(fmaf(S[j][3], LOG2E, -SHIFT_L2));
                lac[j] += (p0 + p1) + (p2 + p3);
                __hip_bfloat162 q01 = __float22bfloat162_rn(make_float2(p0, p1));
                __hip_bfloat162 q23 = __float22bfloat162_rn(make_float2(p2, p3));
                __builtin_memcpy(&paA[j][0], &q01, 4);
                __builtin_memcpy(&paA[j][1], &q23, 4);
            }
        }

        // ---- chunk B: ph1 + exp -> paB (regs 2..3); zeros on the odd tail
        unsigned int paB[2][2] = {{0u, 0u}, {0u, 0u}};
        if (hasB) {
            f32x4 S[2] = {};
#pragma unroll
            for (int ki = 0; ki < 2; ++ki) {
                short8 ah = *(const short8*)&MhiB[aoff0 + ki * 32];
#pragma unroll
                for (int j = 0; j < 2; ++j) {
                    S[j] = __builtin_amdgcn_mfma_f32_16x16x32_bf16(ah, xh[j][ki], S[j], 0, 0, 0);
                    S[j] = __builtin_amdgcn_mfma_f32_16x16x32_bf16(ah, xl[j][ki], S[j], 0, 0, 0);
                }
            }
#pragma unroll
            for (int j = 0; j < 2; ++j) {
                float p0 = __builtin_amdgcn_exp2f(fmaf(S[j][0], LOG2E, -SHIFT_L2));
                float p1 = __builtin_amdgcn_exp2f(fmaf(S[j][1], LOG2E, -SHIFT_L2));
                float p2 = __builtin_amdgcn_exp2f(fmaf(S[j][2], LOG2E, -SHIFT_L2));
                float p3 = __builtin_amdgcn_exp2f(fmaf(S[j][3], LOG2E, -SHIFT_L2));
                lac[j] += (p0 + p1) + (p2 + p3);
                __hip_bfloat162 q01 = __float22bfloat162_rn(make_float2(p0, p1));
                __hip_bfloat162 q23 = __float22bfloat162_rn(make_float2(p2, p3));
                __builtin_memcpy(&paB[j][0], &q01, 4);
                __builtin_memcpy(&paB[j][1], &q23, 4);
            }
        }

        // ---- combined ph2: U += [P_A | P_B] . [Mt_A | Mt_B], 8 full-rate K=32 MFMAs
#pragma unroll
        for (int dt = 0; dt < 4; ++dt) {
            int boff = (dt * 16 + lq) * STR + boffb;   // 8B-aligned
            union { short8 s8; unsigned int u[4]; } bm;
            bm.u[0] = *(const unsigned int*)&MtA[boff];
            bm.u[1] = *(const unsigned int*)&MtA[boff + 2];
            bm.u[2] = *(const unsigned int*)&MtB[boff];       // stale on tail: x0 below
            bm.u[3] = *(const unsigned int*)&MtB[boff + 2];
#pragma unroll
            for (int j = 0; j < 2; ++j) {
                union { short8 s8; unsigned int u[4]; } pa;
                pa.u[0] = paA[j][0]; pa.u[1] = paA[j][1];
                pa.u[2] = paB[j][0]; pa.u[3] = paB[j][1];
                Uacc[j][dt] = __builtin_amdgcn_mfma_f32_16x16x32_bf16(pa.s8, bm.s8, Uacc[j][dt], 0, 0, 0);
            }
        }
    }

    // l reduction across quads (lane^16, lane^32 share a batch column)
    for (int j = 0; j < 2; ++j) {
        float v = lac[j];
        v += __shfl_xor(v, 16);
        v += __shfl_xor(v, 32);
        if (quad == 0) lsc[mblk][(nt0 + j) * 16 + lq] = v;
    }

    // U reduction across the 4 k-slice waves, in LDS (reuse buf0/1 as float [64][66])
    float* Ured = (float*)lds;
#pragma unroll
    for (int rnd = 0; rnd < 4; ++rnd) {
        __syncthreads();
        if (mblk == rnd) {
#pragma unroll
            for (int j = 0; j < 2; ++j)
#pragma unroll
                for (int dt = 0; dt < 4; ++dt)
#pragma unroll
                    for (int r4 = 0; r4 < 4; ++r4) {
                        int row = (nt0 + j) * 16 + quad * 4 + r4;
                        int col = dt * 16 + lq;
                        if (rnd == 0) Ured[row * 66 + col] = Uacc[j][dt][r4];
                        else          Ured[row * 66 + col] += Uacc[j][dt][r4];
                    }
        }
    }
    __syncthreads();

    // atomic-accumulate partials into the single [2048][52] buffer (r17; ulp-level order)
    float* pp = part + (size_t)b0 * PSTRIDE;
    for (int i = t; i < BT * D_SZ; i += 512) {
        int row = i / D_SZ, d = i - row * D_SZ;
        atomicAdd(&pp[(size_t)row * PSTRIDE + d], Ured[row * 66 + d]);
    }
    if (t < BT) {
        float Ls = lsc[0][t] + lsc[1][t] + lsc[2][t] + lsc[3][t];
        atomicAdd(&pp[(size_t)t * PSTRIDE + D_SZ], Ls);
    }

    // r24: last contributor block per xtile normalizes + writes out.
    // Ordering: per-wave vmcnt drain (atomics COMPLETE at coherence point) -> barrier ->
    // ticket. NO __threadfence (r23: L2 writeback serialization, +140us).
    asm volatile("s_waitcnt vmcnt(0)" ::: "memory");
    __syncthreads();
    if (t == 0) {
        unsigned int old = atomicAdd(&cnt[xtile], 1u);
        lastFlag = (old == (unsigned int)(nsplit - 1));
    }
    __syncthreads();
    if (lastFlag) {
        if (t < BT) Lrow[t] = atomicAdd(&pp[(size_t)t * PSTRIDE + D_SZ], 0.f);
        __syncthreads();
        for (int i = t; i < BT * D_SZ; i += 512) {
            int row = i / D_SZ, d = i - row * D_SZ;
            int gb = b0 + row;
            float acc = atomicAdd(&pp[(size_t)row * PSTRIDE + d], 0.f);
            out[(size_t)gb * (2 * D_SZ) + d] = x[(size_t)gb * D_SZ + d];
            out[(size_t)gb * (2 * D_SZ) + D_SZ + d] = acc / Lrow[row];
        }
    }
}

// ---------------- fallback (round-2 kernel) for small ws ----------------
__global__ __launch_bounds__(512, 4)
void attend_partial_v2(const float* __restrict__ x, const float* __restrict__ M,
                       float* __restrict__ part, int slice) {
    __shared__ __align__(16) unsigned short lds[4 * 64 * STR];
    __shared__ float lsc[4][64];
    unsigned short* bufA  = lds;
    unsigned short* bufB  = lds + 64 * STR;
    unsigned short* Mc_hi = lds + 2 * 64 * STR;
    unsigned short* Mc_lo = lds + 3 * 64 * STR;

    const int t = threadIdx.x;
    const int w = t >> 6, lane = t & 63;
    const int quad = lane >> 4, lq = lane & 15;
    const int b0 = blockIdx.x * 64;
    const int split = blockIdx.y;
    const int kbeg = split * slice;
    const int kend = min(kbeg + slice, K_SZ);

    for (int i = t; i < 4 * 64 * STR; i += 512) lds[i] = 0;
    __syncthreads();
    for (int i = t; i < 64 * 25; i += 512) {
        int r = i / 25, cp = i - r * 25, c = cp * 2;
        float2 v = *(const float2*)&x[(size_t)(b0 + r) * D_SZ + c];
        unsigned short h0 = bf16_rne(v.x), h1 = bf16_rne(v.y);
        unsigned short l0 = bf16_rne(v.x - bf16_to_f(h0));
        unsigned short l1 = bf16_rne(v.y - bf16_to_f(h1));
        *(unsigned int*)&bufA[r * STR + c] = ((unsigned int)h1 << 16) | h0;
        *(unsigned int*)&bufB[r * STR + c] = ((unsigned int)l1 << 16) | l0;
    }
    __syncthreads();

    const int nt0 = (w & 1) * 2;
    const int mblk = w >> 1;
    short8 xh[2][2], xl[2][2];
    for (int j = 0; j < 2; ++j)
        for (int ki = 0; ki < 2; ++ki) {
            int off = ((nt0 + j) * 16 + lq) * STR + ki * 32 + quad * 8;
            xh[j][ki] = *(const short8*)&bufA[off];
            xl[j][ki] = *(const short8*)&bufB[off];
        }

    f32x4 Uacc[2] = {};
    float lac[2] = {0.f, 0.f};

    for (int k0 = kbeg; k0 < kend; k0 += CK) {
        __syncthreads();
        for (int i = t; i < 64 * 25; i += 512) {
            int r = i / 25, cp = i - r * 25, c = cp * 2;
            int kg = k0 + r;
            float2 v = make_float2(0.f, 0.f);
            if (kg < kend) v = *(const float2*)&M[(size_t)kg * D_SZ + c];
            unsigned short h0 = bf16_rne(v.x), h1 = bf16_rne(v.y);
            unsigned short l0 = bf16_rne(v.x - bf16_to_f(h0));
            unsigned short l1 = bf16_rne(v.y - bf16_to_f(h1));
            *(unsigned int*)&Mc_hi[r * STR + c] = ((unsigned int)h1 << 16) | h0;
            *(unsigned int*)&Mc_lo[r * STR + c] = ((unsigned int)l1 << 16) | l0;
            bufB[c * STR + r] = h0;
            bufB[(c + 1) * STR + r] = h1;
        }
        __syncthreads();

        f32x4 S[2] = {};
        for (int ki = 0; ki < 2; ++ki) {
            int aoff = (mblk * 16 + lq) * STR + ki * 32 + quad * 8;
            short8 ah = *(const short8*)&Mc_hi[aoff];
            short8 al = *(const short8*)&Mc_lo[aoff];
            for (int j = 0; j < 2; ++j) {
                S[j] = __builtin_amdgcn_mfma_f32_16x16x32_bf16(ah, xh[j][ki], S[j], 0, 0, 0);
                S[j] = __builtin_amdgcn_mfma_f32_16x16x32_bf16(ah, xl[j][ki], S[j], 0, 0, 0);
                S[j] = __builtin_amdgcn_mfma_f32_16x16x32_bf16(al, xh[j][ki], S[j], 0, 0, 0);
            }
        }
        for (int j = 0; j < 2; ++j) {
            unsigned short pb4[4];
#pragma unroll
            for (int r4 = 0; r4 < 4; ++r4) {
                float p = __expf(S[j][r4] - SHIFT);
                lac[j] += p;
                pb4[r4] = bf16_rne(p);
            }
            int b = (nt0 + j) * 16 + lq;
            int n0 = mblk * 16 + quad * 4;
            *(unsigned int*)&bufA[b * STR + n0]     = ((unsigned int)pb4[1] << 16) | pb4[0];
            *(unsigned int*)&bufA[b * STR + n0 + 2] = ((unsigned int)pb4[3] << 16) | pb4[2];
        }
        __syncthreads();
        for (int ki = 0; ki < 2; ++ki) {
            int poff = (mblk * 16 + lq) * STR + ki * 32 + quad * 8;
            short8 ap = *(const short8*)&bufA[poff];
            for (int j = 0; j < 2; ++j) {
                int doff = ((nt0 + j) * 16 + lq) * STR + ki * 32 + quad * 8;
                short8 bm = *(const short8*)&bufB[doff];
                Uacc[j] = __builtin_amdgcn_mfma_f32_16x16x32_bf16(ap, bm, Uacc[j], 0, 0, 0);
            }
        }
    }

    for (int j = 0; j < 2; ++j) {
        float v = lac[j];
        v += __shfl_xor(v, 16);
        v += __shfl_xor(v, 32);
        if (quad == 0) lsc[mblk][(nt0 + j) * 16 + lq] = v;
    }
    __syncthreads();
    float* pp = part + ((size_t)split * B_SZ + b0) * PSTRIDE;
    for (int j = 0; j < 2; ++j) {
        int d = (nt0 + j) * 16 + lq;
        if (d < D_SZ) {
#pragma unroll
            for (int r4 = 0; r4 < 4; ++r4) {
                int b = mblk * 16 + quad * 4 + r4;
                pp[(size_t)b * PSTRIDE + d] = Uacc[j][r4];
            }
        }
    }
    if (t < 64) {
        float Ls = lsc[0][t] + lsc[1][t] + lsc[2][t] + lsc[3][t];
        pp[(size_t)t * PSTRIDE + D_SZ] = Ls;
    }
}

// combine for the fallback path: per-split partial slots
__global__ __launch_bounds__(256)
void combine(const float* __restrict__ x, const float* __restrict__ part,
             float* __restrict__ out, int nsplit) {
    const int b = blockIdx.x * 4 + (threadIdx.x >> 6);
    const int t = threadIdx.x & 63;
    float L = 0.f;
    for (int s = 0; s < nsplit; ++s)
        L += part[((size_t)s * B_SZ + b) * PSTRIDE + D_SZ];
    if (t < D_SZ) {
        float acc = 0.f;
        for (int s = 0; s < nsplit; ++s)
            acc += part[((size_t)s * B_SZ + b) * PSTRIDE + t];
        out[(size_t)b * (2 * D_SZ) + t] = x[(size_t)b * D_SZ + t];
        out[(size_t)b * (2 * D_SZ) + D_SZ + t] = acc / L;
    }
}

extern "C" void kernel_launch(void* const* d_in, const int* in_sizes, int n_in,
                              void* d_out, int out_size, void* d_ws, size_t ws_size,
                              hipStream_t stream) {
    const float* x = (const float*)d_in[0];
    const float* M = (const float*)d_in[1];
    float* out = (float*)d_out;
    const size_t per_split = (size_t)B_SZ * PSTRIDE * sizeof(float);

    if (ws_size >= IMG_BYTES + PART_BYTES + 128) {
        unsigned short* img = (unsigned short*)d_ws;
        float* part = (float*)((char*)d_ws + IMG_BYTES);
        unsigned int* cnt = (unsigned int*)((char*)d_ws + IMG_BYTES + PART_BYTES);
        const int ns = 32;
        int slice = (((K_SZ + ns - 1) / ns) + 127) & ~127;   // 3200: 128-aligned
        precompute_m<<<NCH, 256, 0, stream>>>(M, img, part, cnt);  // also zeroes part+cnt
        attend_fast<<<32 * ns, 512, 0, stream>>>(x, img, part, cnt, out, slice, ns);
    } else {
        float* part = (float*)d_ws;
        int ns = (int)(ws_size / per_split);
        if (ns > 32) ns = 32;
        if (ns < 1) ns = 1;
        int slice = (K_SZ + ns - 1) / ns;
        dim3 gridA(B_SZ / 64, ns);
        attend_partial_v2<<<gridA, 512, 0, stream>>>(x, M, part, slice);
        combine<<<B_SZ / 4, 256, 0, stream>>>(x, part, out, ns);
    }
}

// Round 12
// 166.817 us; speedup vs baseline: 1.8089x; 1.0723x over previous
//
#include <hip/hip_runtime.h>
#include <hip/hip_bf16.h>
#include <math.h>

#define B_SZ 2048
#define K_SZ 100000
#define D_SZ 50
#define BT   64       // batch rows per block (8 waves, 512 thr, j=2). r14/r20/r22: finer wave
                      // decomps and per-wave pipelines all regress. Keep the r13/r19 structure.
#define CK   64       // r15 measured CK=128 image: regression. 64-k chunks; r19 pairs two
                      // chunks into one K=32 ph2 (lower/upper MFMA slots, no shuffles).
#define STR  72        // img row stride in 2B units; 144 B
#define MTS  78        // precompute Mt scratch stride (odd dword stride -> ~2-way scatter)
#define SHIFT 30.0f    // bf16 P: fp32 exponent range, no subnormal cliff (f16 failed r4)
#define LOG2E 1.4426950408889634f
#define SHIFT_L2 43.280851226668905f   // SHIFT * LOG2E
#define PSTRIDE 52
#define NCH   1563     // ceil(100000/64)
#define IMG_CH 9216    // 2B units per chunk image: 2 * 64 * STR  ([Mhi bf16 | Mt bf16])
#define IMG_BYTES ((size_t)NCH * IMG_CH * 2)
#define NSEG  18       // 1024B segments per chunk image (18432 B)
#define PART_BYTES ((size_t)B_SZ * PSTRIDE * sizeof(float))

typedef short short8 __attribute__((ext_vector_type(8)));
typedef short short4v __attribute__((ext_vector_type(4)));
typedef float f32x4 __attribute__((ext_vector_type(4)));

__device__ __forceinline__ unsigned short bf16_rne(float f) {
    union { float f; unsigned int u; } v; v.f = f;
    unsigned int r = (v.u + 0x7fffu + ((v.u >> 16) & 1u)) >> 16;
    return (unsigned short)r;
}
__device__ __forceinline__ float bf16_to_f(unsigned short h) {
    union { unsigned int u; float f; } v; v.u = ((unsigned int)h) << 16;
    return v.f;
}

// async global->LDS, 16B per lane; LDS dest = wave-uniform base + lane*16 (m97/m104 semantics)
__device__ __forceinline__ void load_lds16(const void* g, void* l) {
    __builtin_amdgcn_global_load_lds(
        (const __attribute__((address_space(1))) unsigned int*)g,
        (__attribute__((address_space(3))) unsigned int*)l, 16, 0, 0);
}

// ---------------- prologue: M -> per-chunk image [Mhi bf16 | Mt bf16] ----------------
// r7 structure, de-conflicted scatter (MTS=78). NO __threadfence (r11: +120us; r23
// re-measured the same failure in attend: per-block L2 writeback serialized, 113->255us).
// Zeroes the atomic partial buffer (folds out the memset dispatch — r21, measured harmless).
// r25: Mt d-row 50 = bf16(1.0) — the ones-column. ph2's MFMA then accumulates sum_k P
// into output col 50 (= the L slot of part), deleting attend's lac adds + shuffle reduce.
// Rows 51..63 stay zero.
__global__ __launch_bounds__(256)
void precompute_m(const float* __restrict__ M, unsigned short* __restrict__ img,
                  float* __restrict__ part) {
    __shared__ __align__(16) unsigned short Mt[64 * MTS];   // transpose scratch (9984 B)
    const int t = threadIdx.x;
    const int c0 = blockIdx.x;
    const int k0 = c0 * 64;
    for (int i = c0 * 256 + t; i < B_SZ * PSTRIDE; i += NCH * 256) part[i] = 0.f;
    for (int i = t; i < (64 * MTS) / 2; i += 256) ((unsigned int*)Mt)[i] = 0;
    __syncthreads();
    unsigned int* gh = (unsigned int*)(img + (size_t)c0 * IMG_CH);   // 2304 dwords
    for (int i = t; i < 64 * 36; i += 256) {
        int r = i / 36, cd = i - r * 36, c = cd * 2;
        int kg = k0 + r;
        unsigned int val = 0;
        if (kg < K_SZ && c < D_SZ) {
            float2 v = *(const float2*)&M[(size_t)kg * D_SZ + c];
            val = ((unsigned int)bf16_rne(v.y) << 16) | bf16_rne(v.x);
            Mt[c * MTS + r]       = (unsigned short)(val & 0xffffu);  // one-time transpose
            Mt[(c + 1) * MTS + r] = (unsigned short)(val >> 16);
        }
        gh[i] = val;
    }
    // ones-column: Mt row 50 (scatter above only touches rows c<50 — no race).
    // Pad k-rows (kg>=K_SZ) contribute exp(-30)*1 ~ 9e-14 to L, same as the old lac.
    for (int i = t; i < 64; i += 256) Mt[50 * MTS + i] = 0x3f80;   // bf16(1.0)
    __syncthreads();
    // copy-out: image d-row r, dwords c=0..35 (u16 pairs 2c,2c+1; cols >=64 are zero pad)
    unsigned int* gt = (unsigned int*)(img + (size_t)c0 * IMG_CH + 64 * STR);
    for (int i = t; i < 64 * 36; i += 256) {
        int r = i / 36, c = i - r * 36;
        gt[i] = *(const unsigned int*)&Mt[r * MTS + c * 2];   // dword-aligned (MTS even)
    }
}

// ---------------- hot kernel (r19 body + r25 ones-column l) ----------------
// ph1: S[mem][batch] = Mhi . (xh + xl)^T per chunk (2-pass x-side hi/lo). exp in regs.
// ph2: ONE K=32 16x16x32 MFMA pass per chunk PAIR (lower/upper 4 A/B slots = chunks n/n+1;
//      slot pairing is k-agnostic). Staging: r18 quad-buffer, drain+barrier per pair.
// r25: L = sum_k P computed by the MFMA via Mt's ones-row-50 (col 50 of Uacc[j][3]) —
//      lac adds, shuffle reduce, and lsc are deleted; epilogue writes 64x51 (d=50 is the
//      L slot). L now sums bf16(P), CONSISTENT with the numerator (also bf16 P).
// r24's fused combine reverted: measured dispatch overhead ~0.5us each (r17 vs r24
// total-minus-attend 61.5 vs 60.5), while the fused epilogue cost attend +5us.
// launch_bounds MUST stay (512,4): r16 measured (512,8) -> 32-VGPR alloc, x-frag spill,
// 1.9GB scratch FETCH, 577us.
__global__ __launch_bounds__(512, 4)
void attend_fast(const float* __restrict__ x, const unsigned short* __restrict__ img,
                 float* __restrict__ part, int slice) {
    __shared__ __align__(16) unsigned short lds[4 * IMG_CH];   // quad-buf; buf0/1 reused as Ured

    const int t = threadIdx.x;
    const int w = t >> 6, lane = t & 63;
    const int quad = lane >> 4, lq = lane & 15;

    const int bid = blockIdx.x;
    const int rr = bid >> 3;
    const int split = (rr >> 5) * 8 + (bid & 7);   // same split -> same XCD (perf heuristic)
    const int xtile = rr & 31;
    const int b0 = xtile * BT;
    const int kbeg = split * slice;
    const int kend = min(kbeg + slice, K_SZ);

    const int nt0 = (w & 1) * 2;   // this wave's pair of batch 16-tiles
    const int mblk = w >> 1;       // this wave's memrow 16-tile (= its ph2 k-slice)

    // x fragments: direct global load + hi/lo bf16 split (K-loop invariant, cold path)
    short8 xh[2][2], xl[2][2];
    for (int j = 0; j < 2; ++j) {
        int row = b0 + (nt0 + j) * 16 + lq;
        const float* xr = x + (size_t)row * D_SZ;
        for (int ki = 0; ki < 2; ++ki) {
            int d0 = ki * 32 + quad * 8;
            float v[8];
#pragma unroll
            for (int e = 0; e < 8; ++e) v[e] = 0.f;
            if (d0 + 8 <= D_SZ) {
#pragma unroll
                for (int e = 0; e < 4; ++e) {
                    float2 f2 = *(const float2*)&xr[d0 + 2 * e];
                    v[2 * e] = f2.x; v[2 * e + 1] = f2.y;
                }
            } else if (d0 < D_SZ) {            // d0 == 48
                float2 f2 = *(const float2*)&xr[d0];
                v[0] = f2.x; v[1] = f2.y;
            }
            short8 sh, sl;
#pragma unroll
            for (int e = 0; e < 8; ++e) {
                unsigned short h = bf16_rne(v[e]);
                sh[e] = (short)h;
                sl[e] = (short)bf16_rne(v[e] - bf16_to_f(h));
            }
            xh[j][ki] = sh; xl[j][ki] = sl;
        }
    }

    f32x4 Uacc[2][4] = {};         // [batch tile j][d tile dt]; col 50 of dt=3 carries L

    const int ci0 = kbeg >> 6;
    const int nch = (kend - kbeg + CK - 1) / CK;
    const int r0 = bid % nch;      // per-block rotation (de-phase co-resident blocks)

    // prologue DMA: rotated chunks seq[0] -> buf0, seq[1] -> buf1
    {
        const unsigned short* g = img + (size_t)(ci0 + r0) * IMG_CH;
        for (int seg = w; seg < NSEG; seg += 8)
            load_lds16((const unsigned int*)(g + seg * 512) + lane * 4, lds + seg * 512);
        if (nch > 1) {
            int c1 = r0 + 1; if (c1 >= nch) c1 -= nch;
            const unsigned short* g1 = img + (size_t)(ci0 + c1) * IMG_CH;
            for (int seg = w; seg < NSEG; seg += 8)
                load_lds16((const unsigned int*)(g1 + seg * 512) + lane * 4,
                           lds + IMG_CH + seg * 512);
        }
    }

    const int aoff0 = (mblk * 16 + lq) * STR + quad * 8;           // ph1 Mhi read base
    const int boffb = mblk * 16 + quad * 4;                        // ph2 Mt k-col base

    for (int n = 0; n < nch; n += 2) {
        __builtin_amdgcn_s_waitcnt(0);   // drain own DMA (vm+lgkm) — issued >=1 pair ago
        __syncthreads();                 // chunks n,n+1 visible; fences last pair's reads
                                         // of the two buffers we are about to overwrite
#pragma unroll
        for (int f = 2; f <= 3; ++f) {   // prefetch chunks n+2, n+3 (rotated order)
            int nn = n + f;
            if (nn < nch) {
                int cc = r0 + nn; if (cc >= nch) cc -= nch;
                const unsigned short* g = img + (size_t)(ci0 + cc) * IMG_CH;
                unsigned short* dst = lds + (size_t)(nn & 3) * IMG_CH;
                for (int seg = w; seg < NSEG; seg += 8)
                    load_lds16((const unsigned int*)(g + seg * 512) + lane * 4,
                               dst + seg * 512);
            }
        }

        const int hasB = (n + 1 < nch);                 // block-uniform
        const unsigned short* MhiA = lds + (size_t)(n & 3) * IMG_CH;
        const unsigned short* MtA  = MhiA + 64 * STR;
        const unsigned short* MhiB = lds + (size_t)((n + 1) & 3) * IMG_CH;
        const unsigned short* MtB  = MhiB + 64 * STR;

        // ---- chunk A: ph1 + exp -> paA (packed bf16 pairs, regs 0..1 of the pair op)
        unsigned int paA[2][2];
        {
            f32x4 S[2] = {};
#pragma unroll
            for (int ki = 0; ki < 2; ++ki) {
                short8 ah = *(const short8*)&MhiA[aoff0 + ki * 32];
#pragma unroll
                for (int j = 0; j < 2; ++j) {
                    S[j] = __builtin_amdgcn_mfma_f32_16x16x32_bf16(ah, xh[j][ki], S[j], 0, 0, 0);
                    S[j] = __builtin_amdgcn_mfma_f32_16x16x32_bf16(ah, xl[j][ki], S[j], 0, 0, 0);
                }
            }
#pragma unroll
            for (int j = 0; j < 2; ++j) {
                float p0 = __builtin_amdgcn_exp2f(fmaf(S[j][0], LOG2E, -SHIFT_L2));
                float p1 = __builtin_amdgcn_exp2f(fmaf(S[j][1], LOG2E, -SHIFT_L2));
                float p2 = __builtin_amdgcn_exp2f(fmaf(S[j][2], LOG2E, -SHIFT_L2));
                float p3 = __builtin_amdgcn_exp2f(fmaf(S[j][3], LOG2E, -SHIFT_L2));
                __hip_bfloat162 q01 = __float22bfloat162_rn(make_float2(p0, p1));
                __hip_bfloat162 q23 = __float22bfloat162_rn(make_float2(p2, p3));
                __builtin_memcpy(&paA[j][0], &q01, 4);
                __builtin_memcpy(&paA[j][1], &q23, 4);
            }
        }

        // ---- chunk B: ph1 + exp -> paB (regs 2..3); zeros on the odd tail
        unsigned int paB[2][2] = {{0u, 0u}, {0u, 0u}};
        if (hasB) {
            f32x4 S[2] = {};
#pragma unroll
            for (int ki = 0; ki < 2; ++ki) {
                short8 ah = *(const short8*)&MhiB[aoff0 + ki * 32];
#pragma unroll
                for (int j = 0; j < 2; ++j) {
                    S[j] = __builtin_amdgcn_mfma_f32_16x16x32_bf16(ah, xh[j][ki], S[j], 0, 0, 0);
                    S[j] = __builtin_amdgcn_mfma_f32_16x16x32_bf16(ah, xl[j][ki], S[j], 0, 0, 0);
                }
            }
#pragma unroll
            for (int j = 0; j < 2; ++j) {
                float p0 = __builtin_amdgcn_exp2f(fmaf(S[j][0], LOG2E, -SHIFT_L2));
                float p1 = __builtin_amdgcn_exp2f(fmaf(S[j][1], LOG2E, -SHIFT_L2));
                float p2 = __builtin_amdgcn_exp2f(fmaf(S[j][2], LOG2E, -SHIFT_L2));
                float p3 = __builtin_amdgcn_exp2f(fmaf(S[j][3], LOG2E, -SHIFT_L2));
                __hip_bfloat162 q01 = __float22bfloat162_rn(make_float2(p0, p1));
                __hip_bfloat162 q23 = __float22bfloat162_rn(make_float2(p2, p3));
                __builtin_memcpy(&paB[j][0], &q01, 4);
                __builtin_memcpy(&paB[j][1], &q23, 4);
            }
        }

        // ---- combined ph2: U += [P_A | P_B] . [Mt_A | Mt_B], 8 full-rate K=32 MFMAs
        // (col 50 = ones-row -> accumulates sum_k P = L)
#pragma unroll
        for (int dt = 0; dt < 4; ++dt) {
            int boff = (dt * 16 + lq) * STR + boffb;   // 8B-aligned
            union { short8 s8; unsigned int u[4]; } bm;
            bm.u[0] = *(const unsigned int*)&MtA[boff];
            bm.u[1] = *(const unsigned int*)&MtA[boff + 2];
            bm.u[2] = *(const unsigned int*)&MtB[boff];       // stale on tail: x0 below
            bm.u[3] = *(const unsigned int*)&MtB[boff + 2];
#pragma unroll
            for (int j = 0; j < 2; ++j) {
                union { short8 s8; unsigned int u[4]; } pa;
                pa.u[0] = paA[j][0]; pa.u[1] = paA[j][1];
                pa.u[2] = paB[j][0]; pa.u[3] = paB[j][1];
                Uacc[j][dt] = __builtin_amdgcn_mfma_f32_16x16x32_bf16(pa.s8, bm.s8, Uacc[j][dt], 0, 0, 0);
            }
        }
    }

    // U reduction across the 4 k-slice waves, in LDS (reuse buf0/1 as float [64][66])
    float* Ured = (float*)lds;
#pragma unroll
    for (int rnd = 0; rnd < 4; ++rnd) {
        __syncthreads();
        if (mblk == rnd) {
#pragma unroll
            for (int j = 0; j < 2; ++j)
#pragma unroll
                for (int dt = 0; dt < 4; ++dt)
#pragma unroll
                    for (int r4 = 0; r4 < 4; ++r4) {
                        int row = (nt0 + j) * 16 + quad * 4 + r4;
                        int col = dt * 16 + lq;
                        if (rnd == 0) Ured[row * 66 + col] = Uacc[j][dt][r4];
                        else          Ured[row * 66 + col] += Uacc[j][dt][r4];
                    }
        }
    }
    __syncthreads();

    // atomic-accumulate partials (r17; ulp-level order). 64x51: d=50 is the L column.
    float* pp = part + (size_t)b0 * PSTRIDE;
    for (int i = t; i < BT * 51; i += 512) {
        int row = i / 51, d = i - row * 51;
        atomicAdd(&pp[(size_t)row * PSTRIDE + d], Ured[row * 66 + d]);
    }
}

// ---------------- fallback (round-2 kernel) for small ws ----------------
__global__ __launch_bounds__(512, 4)
void attend_partial_v2(const float* __restrict__ x, const float* __restrict__ M,
                       float* __restrict__ part, int slice) {
    __shared__ __align__(16) unsigned short lds[4 * 64 * STR];
    __shared__ float lsc[4][64];
    unsigned short* bufA  = lds;
    unsigned short* bufB  = lds + 64 * STR;
    unsigned short* Mc_hi = lds + 2 * 64 * STR;
    unsigned short* Mc_lo = lds + 3 * 64 * STR;

    const int t = threadIdx.x;
    const int w = t >> 6, lane = t & 63;
    const int quad = lane >> 4, lq = lane & 15;
    const int b0 = blockIdx.x * 64;
    const int split = blockIdx.y;
    const int kbeg = split * slice;
    const int kend = min(kbeg + slice, K_SZ);

    for (int i = t; i < 4 * 64 * STR; i += 512) lds[i] = 0;
    __syncthreads();
    for (int i = t; i < 64 * 25; i += 512) {
        int r = i / 25, cp = i - r * 25, c = cp * 2;
        float2 v = *(const float2*)&x[(size_t)(b0 + r) * D_SZ + c];
        unsigned short h0 = bf16_rne(v.x), h1 = bf16_rne(v.y);
        unsigned short l0 = bf16_rne(v.x - bf16_to_f(h0));
        unsigned short l1 = bf16_rne(v.y - bf16_to_f(h1));
        *(unsigned int*)&bufA[r * STR + c] = ((unsigned int)h1 << 16) | h0;
        *(unsigned int*)&bufB[r * STR + c] = ((unsigned int)l1 << 16) | l0;
    }
    __syncthreads();

    const int nt0 = (w & 1) * 2;
    const int mblk = w >> 1;
    short8 xh[2][2], xl[2][2];
    for (int j = 0; j < 2; ++j)
        for (int ki = 0; ki < 2; ++ki) {
            int off = ((nt0 + j) * 16 + lq) * STR + ki * 32 + quad * 8;
            xh[j][ki] = *(const short8*)&bufA[off];
            xl[j][ki] = *(const short8*)&bufB[off];
        }

    f32x4 Uacc[2] = {};
    float lac[2] = {0.f, 0.f};

    for (int k0 = kbeg; k0 < kend; k0 += CK) {
        __syncthreads();
        for (int i = t; i < 64 * 25; i += 512) {
            int r = i / 25, cp = i - r * 25, c = cp * 2;
            int kg = k0 + r;
            float2 v = make_float2(0.f, 0.f);
            if (kg < kend) v = *(const float2*)&M[(size_t)kg * D_SZ + c];
            unsigned short h0 = bf16_rne(v.x), h1 = bf16_rne(v.y);
            unsigned short l0 = bf16_rne(v.x - bf16_to_f(h0));
            unsigned short l1 = bf16_rne(v.y - bf16_to_f(h1));
            *(unsigned int*)&Mc_hi[r * STR + c] = ((unsigned int)h1 << 16) | h0;
            *(unsigned int*)&Mc_lo[r * STR + c] = ((unsigned int)l1 << 16) | l0;
            bufB[c * STR + r] = h0;
            bufB[(c + 1) * STR + r] = h1;
        }
        __syncthreads();

        f32x4 S[2] = {};
        for (int ki = 0; ki < 2; ++ki) {
            int aoff = (mblk * 16 + lq) * STR + ki * 32 + quad * 8;
            short8 ah = *(const short8*)&Mc_hi[aoff];
            short8 al = *(const short8*)&Mc_lo[aoff];
            for (int j = 0; j < 2; ++j) {
                S[j] = __builtin_amdgcn_mfma_f32_16x16x32_bf16(ah, xh[j][ki], S[j], 0, 0, 0);
                S[j] = __builtin_amdgcn_mfma_f32_16x16x32_bf16(ah, xl[j][ki], S[j], 0, 0, 0);
                S[j] = __builtin_amdgcn_mfma_f32_16x16x32_bf16(al, xh[j][ki], S[j], 0, 0, 0);
            }
        }
        for (int j = 0; j < 2; ++j) {
            unsigned short pb4[4];
#pragma unroll
            for (int r4 = 0; r4 < 4; ++r4) {
                float p = __expf(S[j][r4] - SHIFT);
                lac[j] += p;
                pb4[r4] = bf16_rne(p);
            }
            int b = (nt0 + j) * 16 + lq;
            int n0 = mblk * 16 + quad * 4;
            *(unsigned int*)&bufA[b * STR + n0]     = ((unsigned int)pb4[1] << 16) | pb4[0];
            *(unsigned int*)&bufA[b * STR + n0 + 2] = ((unsigned int)pb4[3] << 16) | pb4[2];
        }
        __syncthreads();
        for (int ki = 0; ki < 2; ++ki) {
            int poff = (mblk * 16 + lq) * STR + ki * 32 + quad * 8;
            short8 ap = *(const short8*)&bufA[poff];
            for (int j = 0; j < 2; ++j) {
                int doff = ((nt0 + j) * 16 + lq) * STR + ki * 32 + quad * 8;
                short8 bm = *(const short8*)&bufB[doff];
                Uacc[j] = __builtin_amdgcn_mfma_f32_16x16x32_bf16(ap, bm, Uacc[j], 0, 0, 0);
            }
        }
    }

    for (int j = 0; j < 2; ++j) {
        float v = lac[j];
        v += __shfl_xor(v, 16);
        v += __shfl_xor(v, 32);
        if (quad == 0) lsc[mblk][(nt0 + j) * 16 + lq] = v;
    }
    __syncthreads();
    float* pp = part + ((size_t)split * B_SZ + b0) * PSTRIDE;
    for (int j = 0; j < 2; ++j) {
        int d = (nt0 + j) * 16 + lq;
        if (d < D_SZ) {
#pragma unroll
            for (int r4 = 0; r4 < 4; ++r4) {
                int b = mblk * 16 + quad * 4 + r4;
                pp[(size_t)b * PSTRIDE + d] = Uacc[j][r4];
            }
        }
    }
    if (t < 64) {
        float Ls = lsc[0][t] + lsc[1][t] + lsc[2][t] + lsc[3][t];
        pp[(size_t)t * PSTRIDE + D_SZ] = Ls;
    }
}

// combine for the atomic path: part is one pre-summed [2048][52] buffer (slot 50 = L)
__global__ __launch_bounds__(256)
void combine_norm(const float* __restrict__ x, const float* __restrict__ part,
                  float* __restrict__ out) {
    const int b = blockIdx.x * 4 + (threadIdx.x >> 6);
    const int t = threadIdx.x & 63;
    if (t < D_SZ) {
        float L = part[(size_t)b * PSTRIDE + D_SZ];
        float acc = part[(size_t)b * PSTRIDE + t];
        out[(size_t)b * (2 * D_SZ) + t] = x[(size_t)b * D_SZ + t];
        out[(size_t)b * (2 * D_SZ) + D_SZ + t] = acc / L;
    }
}

// combine for the fallback path: per-split partial slots
__global__ __launch_bounds__(256)
void combine(const float* __restrict__ x, const float* __restrict__ part,
             float* __restrict__ out, int nsplit) {
    const int b = blockIdx.x * 4 + (threadIdx.x >> 6);
    const int t = threadIdx.x & 63;
    float L = 0.f;
    for (int s = 0; s < nsplit; ++s)
        L += part[((size_t)s * B_SZ + b) * PSTRIDE + D_SZ];
    if (t < D_SZ) {
        float acc = 0.f;
        for (int s = 0; s < nsplit; ++s)
            acc += part[((size_t)s * B_SZ + b) * PSTRIDE + t];
        out[(size_t)b * (2 * D_SZ) + t] = x[(size_t)b * D_SZ + t];
        out[(size_t)b * (2 * D_SZ) + D_SZ + t] = acc / L;
    }
}

extern "C" void kernel_launch(void* const* d_in, const int* in_sizes, int n_in,
                              void* d_out, int out_size, void* d_ws, size_t ws_size,
                              hipStream_t stream) {
    const float* x = (const float*)d_in[0];
    const float* M = (const float*)d_in[1];
    float* out = (float*)d_out;
    const size_t per_split = (size_t)B_SZ * PSTRIDE * sizeof(float);

    if (ws_size >= IMG_BYTES + PART_BYTES) {
        unsigned short* img = (unsigned short*)d_ws;
        float* part = (float*)((char*)d_ws + IMG_BYTES);
        const int ns = 32;
        int slice = (((K_SZ + ns - 1) / ns) + 127) & ~127;   // 3200: 128-aligned
        precompute_m<<<NCH, 256, 0, stream>>>(M, img, part);  // also zeroes part
        attend_fast<<<32 * ns, 512, 0, stream>>>(x, img, part, slice);
        combine_norm<<<B_SZ / 4, 256, 0, stream>>>(x, part, out);
    } else {
        float* part = (float*)d_ws;
        int ns = (int)(ws_size / per_split);
        if (ns > 32) ns = 32;
        if (ns < 1) ns = 1;
        int slice = (K_SZ + ns - 1) / ns;
        dim3 gridA(B_SZ / 64, ns);
        attend_partial_v2<<<gridA, 512, 0, stream>>>(x, M, part, slice);
        combine<<<B_SZ / 4, 256, 0, stream>>>(x, part, out, ns);
    }
}